// Round 1
// baseline (1322.876 us; speedup 1.0000x reference)
//
#include <hip/hip_runtime.h>

#define B_DIM 4
#define S_DIM 4096
#define D_DIM 256
#define L_DIM 8921
#define L_PAD 8960  // 70 * 128

typedef _Float16 f16x8 __attribute__((ext_vector_type(8)));
typedef _Float16 f16x4 __attribute__((ext_vector_type(4)));
typedef float    f32x4 __attribute__((ext_vector_type(4)));

// async 16B global -> LDS (direct, no VGPR round trip)
__device__ __forceinline__ void cp16(_Float16* lds, const _Float16* g) {
  __builtin_amdgcn_global_load_lds(
      (const __attribute__((address_space(1))) unsigned int*)g,
      (__attribute__((address_space(3))) unsigned int*)lds, 16, 0, 0);
}

// ---------------------------------------------------------------------------
// K0a: split x (fp32) -> x_hi, x_lo (f16), elementwise. a = hi + lo to ~2^-22.
// ---------------------------------------------------------------------------
__global__ __launch_bounds__(256) void k_split_x(const float* __restrict__ x,
                                                 _Float16* __restrict__ xh,
                                                 _Float16* __restrict__ xl) {
  const size_t i = ((size_t)blockIdx.x * 256 + threadIdx.x) * 4;
  float4 v = *(const float4*)(x + i);
  f16x4 h, l;
  h.x = (_Float16)v.x; l.x = (_Float16)(v.x - (float)h.x);
  h.y = (_Float16)v.y; l.y = (_Float16)(v.y - (float)h.y);
  h.z = (_Float16)v.z; l.z = (_Float16)(v.z - (float)h.z);
  h.w = (_Float16)v.w; l.w = (_Float16)(v.w - (float)h.w);
  *(f16x4*)(xh + i) = h;
  *(f16x4*)(xl + i) = l;
}

// ---------------------------------------------------------------------------
// K0b: split U (fp32) -> U_hi, U_lo (f16), ZERO-padded to L_PAD rows so that
// k_scores' unmasked global_load_lds staging stays in-bounds and clean.
// ---------------------------------------------------------------------------
__global__ __launch_bounds__(256) void k_split_u(const float* __restrict__ U,
                                                 _Float16* __restrict__ uh,
                                                 _Float16* __restrict__ ul) {
  const size_t i = ((size_t)blockIdx.x * 256 + threadIdx.x) * 4;
  if (i >= (size_t)L_PAD * D_DIM) return;
  float4 v = make_float4(0.f, 0.f, 0.f, 0.f);
  if (i < (size_t)L_DIM * D_DIM) v = *(const float4*)(U + i);
  f16x4 h, l;
  h.x = (_Float16)v.x; l.x = (_Float16)(v.x - (float)h.x);
  h.y = (_Float16)v.y; l.y = (_Float16)(v.y - (float)h.y);
  h.z = (_Float16)v.z; l.z = (_Float16)(v.z - (float)h.z);
  h.w = (_Float16)v.w; l.w = (_Float16)(v.w - (float)h.w);
  *(f16x4*)(uh + i) = h;
  *(f16x4*)(ul + i) = l;
}

// ---------------------------------------------------------------------------
// K0c: xT_hi[b][d][s] = f16(x[b][s][d])  (tiled 32x32 transpose via LDS)
// ---------------------------------------------------------------------------
__global__ __launch_bounds__(256) void k_transpose(const float* __restrict__ x,
                                                   _Float16* __restrict__ xT) {
  __shared__ _Float16 t[32][33];
  const int s0 = blockIdx.x * 32, d0 = blockIdx.y * 32, b = blockIdx.z;
  const float* xb = x + (size_t)b * S_DIM * D_DIM;
  const int r = threadIdx.x >> 5, c = threadIdx.x & 31;
#pragma unroll
  for (int p = 0; p < 4; ++p) {
    const int row = r + p * 8;
    t[row][c] = (_Float16)xb[(size_t)(s0 + row) * D_DIM + d0 + c];
  }
  __syncthreads();
  _Float16* xtb = xT + (size_t)b * D_DIM * S_DIM;
#pragma unroll
  for (int p = 0; p < 4; ++p) {
    const int row = r + p * 8;
    xtb[(size_t)(d0 + row) * S_DIM + s0 + c] = t[c][row];
  }
}

// ---------------------------------------------------------------------------
// K1: scores[b][l][s] = sum_d U[l,d] x[b,s,d]  (fp32 via split-f16 3-product)
// 128x128 tile, BK=32. Staging via global_load_lds(16B) with XOR chunk
// swizzle (both-sides): physical chunk = logical chunk ^ ((row>>1)&3).
// Fused per-row softmax partials {max, sum_exp} over this block's 128 cols.
// grid: (S/128, L_PAD/128, B), block 256 (4 waves, 2x2, each 64x64).
// ---------------------------------------------------------------------------
__global__ __launch_bounds__(256) void k_scores(const _Float16* __restrict__ Uh,
                                                const _Float16* __restrict__ Ul,
                                                const _Float16* __restrict__ Xh,
                                                const _Float16* __restrict__ Xl,
                                                float* __restrict__ scores,
                                                float2* __restrict__ part) {
  const int s0 = blockIdx.x * 128;
  const int l0 = blockIdx.y * 128;
  const int b  = blockIdx.z;

  __shared__ __attribute__((aligned(16))) _Float16 Ah[128 * 32];
  __shared__ __attribute__((aligned(16))) _Float16 Al[128 * 32];
  __shared__ __attribute__((aligned(16))) _Float16 Bh[128 * 32];
  __shared__ __attribute__((aligned(16))) _Float16 Bl[128 * 32];

  const int tid = threadIdx.x;
  const int wave = tid >> 6, lane = tid & 63;
  const int wm = wave & 1, wn = wave >> 1;

  const _Float16* Xbh = Xh + (size_t)b * S_DIM * D_DIM;
  const _Float16* Xbl = Xl + (size_t)b * S_DIM * D_DIM;

  // staging map: thread tid stages 16B at LDS f16-offset tid*8 (+2048 for
  // pass 1) == (row = tid>>2 [+64], physical chunk = tid&3). The data that
  // belongs there is logical chunk (tid&3) ^ q(row), q(row) = (row>>1)&3 =
  // (tid>>3)&3 (invariant across the +64 pass).
  const int srow = tid >> 2;
  const int csrc = ((tid & 3) ^ ((tid >> 3) & 3)) * 8;  // f16 offset in row
  const size_t urow0 = (size_t)(l0 + srow) * D_DIM + csrc;
  const size_t urow1 = urow0 + (size_t)64 * D_DIM;
  const size_t xrow0 = (size_t)(s0 + srow) * D_DIM + csrc;
  const size_t xrow1 = xrow0 + (size_t)64 * D_DIM;
  _Float16* d0 = (_Float16*)0 + tid * 8;  // just offsets; applied per-buffer
  const int ldso = tid * 8;

  // fragment read: logical chunk kg of row R lives at physical chunk
  // kg ^ ((R>>1)&3); with R = base16 + frow this is kg ^ ((frow>>1)&3).
  const int frow = lane & 15;
  const int ck = ((lane >> 4) ^ ((frow >> 1) & 3)) * 8;

  f32x4 acc[4][4] = {};

  for (int k0 = 0; k0 < D_DIM; k0 += 32) {
    cp16(Ah + ldso,        Uh + urow0 + k0);
    cp16(Ah + 2048 + ldso, Uh + urow1 + k0);
    cp16(Al + ldso,        Ul + urow0 + k0);
    cp16(Al + 2048 + ldso, Ul + urow1 + k0);
    cp16(Bh + ldso,        Xbh + xrow0 + k0);
    cp16(Bh + 2048 + ldso, Xbh + xrow1 + k0);
    cp16(Bl + ldso,        Xbl + xrow0 + k0);
    cp16(Bl + 2048 + ldso, Xbl + xrow1 + k0);
    __syncthreads();  // drains vmcnt (global_load_lds) before reads

    f16x8 ah[4], al[4], bh[4], bl[4];
#pragma unroll
    for (int i = 0; i < 4; ++i) {
      const int ra = (wm * 64 + i * 16 + frow) * 32 + ck;
      const int rb = (wn * 64 + i * 16 + frow) * 32 + ck;
      ah[i] = *(const f16x8*)(Ah + ra);
      al[i] = *(const f16x8*)(Al + ra);
      bh[i] = *(const f16x8*)(Bh + rb);
      bl[i] = *(const f16x8*)(Bl + rb);
    }
#pragma unroll
    for (int i = 0; i < 4; ++i)
#pragma unroll
      for (int j = 0; j < 4; ++j) {
        acc[i][j] = __builtin_amdgcn_mfma_f32_16x16x32_f16(ah[i], bh[j], acc[i][j], 0, 0, 0);
        acc[i][j] = __builtin_amdgcn_mfma_f32_16x16x32_f16(ah[i], bl[j], acc[i][j], 0, 0, 0);
        acc[i][j] = __builtin_amdgcn_mfma_f32_16x16x32_f16(al[i], bh[j], acc[i][j], 0, 0, 0);
      }
    __syncthreads();
  }
  (void)d0;

  // ---- C write (raw scores, fp32) ----
  float* sc = scores + (size_t)b * L_DIM * S_DIM;
  const int hi = lane >> 4;
#pragma unroll
  for (int i = 0; i < 4; ++i)
#pragma unroll
    for (int j = 0; j < 4; ++j) {
      const int col = s0 + wn * 64 + j * 16 + (lane & 15);
#pragma unroll
      for (int r = 0; r < 4; ++r) {
        const int row = l0 + wm * 64 + i * 16 + hi * 4 + r;
        if (row < L_DIM) sc[(size_t)row * S_DIM + col] = acc[i][j][r];
      }
    }

  // ---- fused softmax partials over this block's 128 s-columns ----
  // per row: max over {j x 16 lanes} (64 cols per wave), then sum of exp.
  // Combine the two wn-waves via LDS (reuse Ah, dead after last sync).
  float* redm = (float*)Ah;        // [2][2][64] : [wm][wn][row64]
  float* reds = redm + 256;
#pragma unroll
  for (int i = 0; i < 4; ++i)
#pragma unroll
    for (int r = 0; r < 4; ++r) {
      float m = fmaxf(fmaxf(acc[i][0][r], acc[i][1][r]),
                      fmaxf(acc[i][2][r], acc[i][3][r]));
      m = fmaxf(m, __shfl_xor(m, 1));
      m = fmaxf(m, __shfl_xor(m, 2));
      m = fmaxf(m, __shfl_xor(m, 4));
      m = fmaxf(m, __shfl_xor(m, 8));
      float s = __expf(acc[i][0][r] - m) + __expf(acc[i][1][r] - m) +
                __expf(acc[i][2][r] - m) + __expf(acc[i][3][r] - m);
      s += __shfl_xor(s, 1);
      s += __shfl_xor(s, 2);
      s += __shfl_xor(s, 4);
      s += __shfl_xor(s, 8);
      if ((lane & 15) == 0) {
        const int row64 = i * 16 + hi * 4 + r;
        redm[(wm * 2 + wn) * 64 + row64] = m;
        reds[(wm * 2 + wn) * 64 + row64] = s;
      }
    }
  __syncthreads();
  if (tid < 128) {
    const int wmm = tid >> 6, r64 = tid & 63;
    const float m0 = redm[(wmm * 2 + 0) * 64 + r64];
    const float m1 = redm[(wmm * 2 + 1) * 64 + r64];
    const float s0v = reds[(wmm * 2 + 0) * 64 + r64];
    const float s1v = reds[(wmm * 2 + 1) * 64 + r64];
    const float m = fmaxf(m0, m1);
    const float s = s0v * __expf(m0 - m) + s1v * __expf(m1 - m);
    const int l = l0 + tid;
    if (l < L_DIM)
      part[((size_t)blockIdx.x * B_DIM + b) * L_PAD + l] = make_float2(m, s);
  }
}

// ---------------------------------------------------------------------------
// K2: reduce 32 per-s-tile partials -> stats[b][l] = {rowmax, 1/sum}
// layout part[32][B][L_PAD] -> coalesced reads (consecutive l per thread).
// ---------------------------------------------------------------------------
__global__ __launch_bounds__(256) void k_sreduce(const float2* __restrict__ part,
                                                 float* __restrict__ stats) {
  const int idx = blockIdx.x * 256 + threadIdx.x;
  if (idx >= B_DIM * L_DIM) return;
  const int b = idx / L_DIM;
  const int l = idx - b * L_DIM;
  float2 v[32];
#pragma unroll
  for (int t = 0; t < 32; ++t) v[t] = part[((size_t)t * B_DIM + b) * L_PAD + l];
  float m = v[0].x;
#pragma unroll
  for (int t = 1; t < 32; ++t) m = fmaxf(m, v[t].x);
  float s = 0.f;
#pragma unroll
  for (int t = 0; t < 32; ++t) s += v[t].y * __expf(v[t].x - m);
  stats[2 * (size_t)idx]     = m;
  stats[2 * (size_t)idx + 1] = 1.0f / s;
}

// ---------------------------------------------------------------------------
// K3: alpha = softmax(scores) in-place (fp32); out = alpha @ x via f16 MFMA.
// L-tile 32 (was 64): 1116 blocks -> ~2.4x occupancy. LDS stride padded to
// 40 f16 (80 B): (5*row + chunk) % 8 covers all slots -> 2-way (free).
// grid: (ceil(L/32), B), block 256 (4 waves along D, each 32x64).
// ---------------------------------------------------------------------------
__global__ __launch_bounds__(256) void k_out(const _Float16* __restrict__ XT,
                                             const float* __restrict__ stats,
                                             float* __restrict__ alpha,
                                             float* __restrict__ out) {
  const int l0 = blockIdx.x * 32;
  const int b  = blockIdx.y;
  const int tid = threadIdx.x;
  const int wave = tid >> 6, lane = tid & 63;

  __shared__ __attribute__((aligned(16))) _Float16 Aa[32 * 40];
  __shared__ __attribute__((aligned(16))) _Float16 Bb[256 * 40];
  __shared__ float sm[32], sr[32];

  if (tid < 32) {
    const int l = l0 + tid;
    float m = 0.f, r = 0.f;
    if (l < L_DIM) {
      const float* st = stats + ((size_t)b * L_DIM + l) * 2;
      m = st[0];
      r = st[1];
    }
    sm[tid] = m;
    sr[tid] = r;
  }
  __syncthreads();

  f32x4 acc[2][4] = {};
  float* al_base = alpha + (size_t)b * L_DIM * S_DIM;
  const _Float16* xt = XT + (size_t)b * D_DIM * S_DIM;

  const int arow = tid >> 3, aoff = (tid & 7) * 4;  // 32 rows x 32 f32, 1 pass
  const int brow = tid >> 2, boff = (tid & 3) * 8;  // 64 rows/pass x 4
  const float m_r = sm[arow], r_r = sr[arow];
  const int l_a = l0 + arow;
  const int frow = lane & 15, fk = (lane >> 4) * 8;

  for (int s0 = 0; s0 < S_DIM; s0 += 32) {
    float4 v = make_float4(0.f, 0.f, 0.f, 0.f);
    if (l_a < L_DIM) {
      float* ap = al_base + (size_t)l_a * S_DIM + s0 + aoff;
      v = *(const float4*)ap;
      v.x = __expf(v.x - m_r) * r_r;
      v.y = __expf(v.y - m_r) * r_r;
      v.z = __expf(v.z - m_r) * r_r;
      v.w = __expf(v.w - m_r) * r_r;
      *(float4*)ap = v;  // final alpha, fp32-accurate, in-place
    }
    f16x4 pk;
    pk.x = (_Float16)v.x;
    pk.y = (_Float16)v.y;
    pk.z = (_Float16)v.z;
    pk.w = (_Float16)v.w;
    *(f16x4*)(Aa + arow * 40 + aoff) = pk;
#pragma unroll
    for (int p = 0; p < 4; ++p) {
      const int row = brow + p * 64;
      *(uint4*)(Bb + row * 40 + boff) =
          *(const uint4*)(xt + (size_t)row * S_DIM + s0 + boff);
    }
    __syncthreads();

    f16x8 af[2], bf[4];
    af[0] = *(const f16x8*)(Aa + frow * 40 + fk);
    af[1] = *(const f16x8*)(Aa + (16 + frow) * 40 + fk);
#pragma unroll
    for (int j = 0; j < 4; ++j)
      bf[j] = *(const f16x8*)(Bb + (wave * 64 + j * 16 + frow) * 40 + fk);
#pragma unroll
    for (int i = 0; i < 2; ++i)
#pragma unroll
      for (int j = 0; j < 4; ++j)
        acc[i][j] = __builtin_amdgcn_mfma_f32_16x16x32_f16(af[i], bf[j], acc[i][j], 0, 0, 0);
    __syncthreads();
  }

  float* ob = out + (size_t)b * L_DIM * D_DIM;
#pragma unroll
  for (int i = 0; i < 2; ++i)
#pragma unroll
    for (int j = 0; j < 4; ++j) {
      const int d = wave * 64 + j * 16 + (lane & 15);
#pragma unroll
      for (int r = 0; r < 4; ++r) {
        const int l = l0 + i * 16 + (lane >> 4) * 4 + r;
        if (l < L_DIM) ob[(size_t)l * D_DIM + d] = acc[i][j][r];
      }
    }
}

// ---------------------------------------------------------------------------
extern "C" void kernel_launch(void* const* d_in, const int* in_sizes, int n_in,
                              void* d_out, int out_size, void* d_ws, size_t ws_size,
                              hipStream_t stream) {
  const float* x = (const float*)d_in[0];
  const float* U = (const float*)d_in[1];
  float* out   = (float*)d_out;
  float* alpha = out + (size_t)B_DIM * L_DIM * D_DIM;  // raw scores, then alpha

  const size_t NX  = (size_t)B_DIM * S_DIM * D_DIM;  // 4,194,304
  const size_t NUP = (size_t)L_PAD * D_DIM;          // 2,293,760

  // workspace (~43 MB): x_hi, x_lo, xT, U_hi(pad), U_lo(pad), stats, partials
  char* w = (char*)d_ws;
  _Float16* xh = (_Float16*)w; w += NX * 2;
  _Float16* xl = (_Float16*)w; w += NX * 2;
  _Float16* xT = (_Float16*)w; w += NX * 2;
  _Float16* uh = (_Float16*)w; w += NUP * 2;
  _Float16* ul = (_Float16*)w; w += NUP * 2;
  float* stats = (float*)w;    w += (size_t)B_DIM * L_DIM * 2 * sizeof(float);
  float2* part = (float2*)w;   // [32][B][L_PAD]

  k_split_x<<<dim3((unsigned)(NX / 1024)), 256, 0, stream>>>(x, xh, xl);
  k_split_u<<<dim3((unsigned)(NUP / 1024)), 256, 0, stream>>>(U, uh, ul);
  k_transpose<<<dim3(S_DIM / 32, D_DIM / 32, B_DIM), 256, 0, stream>>>(x, xT);
  k_scores<<<dim3(S_DIM / 128, L_PAD / 128, B_DIM), 256, 0, stream>>>(
      uh, ul, xh, xl, alpha, part);
  k_sreduce<<<dim3((B_DIM * L_DIM + 255) / 256), 256, 0, stream>>>(part, stats);
  k_out<<<dim3((L_DIM + 31) / 32, B_DIM), 256, 0, stream>>>(xT, stats, alpha, out);
}